// Round 11
// baseline (178.444 us; speedup 1.0000x reference)
//
#include <hip/hip_runtime.h>

// QuantizedWeight dequant:
//   out[g*8+j] = (cb[0, codes[g,0], j] + cb[1, codes[g,1], j]) * scales[g] + zeros[g]
//
// r11: occupancy-vs-depth discrimination. Exact r8 structure (256 groups per
// wave per super-iteration, 8 named-reg gathers, single LDS buffer) but
// __launch_bounds__(256, 8): cap 64 VGPR -> 8 waves/SIMD = 32 waves/CU (2x r10).
// Potential outstanding gathers unchanged (32x8 = 16x16); if the wall is
// per-wave duty cycle this wins, if it's the per-CU MSHR cap it's null.
//   - kept: fp16 codebook repack in d_ws (entry = 1 dwordx4/lane), per-lane
//     pre-offset codebook base, pair-lane role split + shfl_xor half exchange,
//     half-wave split s/z streams, LDS staging, dense 16 B/lane nt stores.

typedef float    vf4 __attribute__((ext_vector_type(4)));
typedef int      vi4 __attribute__((ext_vector_type(4)));
typedef int      vi2 __attribute__((ext_vector_type(2)));
typedef _Float16 vh2 __attribute__((ext_vector_type(2)));
typedef _Float16 vh8 __attribute__((ext_vector_type(8)));

// ---------------- repack: f32 codebooks -> fp16 copy in workspace ----------
__global__ __launch_bounds__(256) void
repack_kernel(const float* __restrict__ cbs, _Float16* __restrict__ cb16)
{
    const int i = blockIdx.x * blockDim.x + threadIdx.x;   // 131072 threads
    const vf4* in4 = (const vf4*)cbs;
    vf4 a = in4[2 * i];
    vf4 b = in4[2 * i + 1];
    vh8 h;
    h[0] = (_Float16)a.x; h[1] = (_Float16)a.y;
    h[2] = (_Float16)a.z; h[3] = (_Float16)a.w;
    h[4] = (_Float16)b.x; h[5] = (_Float16)b.y;
    h[6] = (_Float16)b.z; h[7] = (_Float16)b.w;
    *(vh8*)(cb16 + (size_t)8 * i) = h;
}

// ---------------- main fp16-gather kernel: depth 8, 32 waves/CU -------------
__global__ __launch_bounds__(256, 8) void
dequant_fp16(const int* __restrict__ codes,
             const _Float16* __restrict__ cb16,   // [2][65536][8] fp16
             const float* __restrict__ cbs,       // f32 original (tail only)
             const float* __restrict__ scales,
             const float* __restrict__ zeros,
             float* __restrict__ out,
             int total)
{
    // per-wave 4 KB: [0,2048) codes int2[256]; [2048,3072) s[256]; [3072,4096) z[256]
    __shared__ __align__(16) char lds_raw[4 * 4096];
    const int lane = threadIdx.x & 63;
    const int wid  = threadIdx.x >> 6;
    char* wlds = lds_raw + wid * 4096;

    const int  nwaves = (gridDim.x * blockDim.x) >> 6;
    const int  wave   = (blockIdx.x * blockDim.x + threadIdx.x) >> 6;
    const long wstep  = (long)nwaves * 256;

    const vi4* codes4 = (const vi4*)codes;

    const int half = lane & 1;            // output half AND entry role
    const int hoff = half * 4;            // float offset of my output half
    const int pidx = lane >> 1;           // pair index 0..31
    const _Float16* mycb = cb16 + ((size_t)half << 19);  // cb1 base for odd lanes

    const float* szsrc = (lane < 32) ? scales : zeros;
    const int    sl    = lane & 31;
    char* szdst = wlds + 2048 + ((lane >> 5) << 10) + (sl << 4);

    long gbase = (long)wave * 256;

    if (gbase + 256 <= total) {
        // prologue stream loads (cover 256 groups)
        vi4 pc0  = __builtin_nontemporal_load(codes4 + (gbase >> 1) + lane);
        vi4 pc1  = __builtin_nontemporal_load(codes4 + (gbase >> 1) + 64 + lane);
        vf4 psz0 = __builtin_nontemporal_load((const vf4*)(szsrc + gbase) + sl);
        vf4 psz1 = __builtin_nontemporal_load((const vf4*)(szsrc + gbase) + 32 + sl);

        for (;;) {
            const long gcur = gbase;
            gbase += wstep;
            const bool more = (gbase + 256 <= total);

            // stage current super-iteration (wave-synchronous, in-order DS)
            *(vi4*)(wlds + lane * 16)        = pc0;
            *(vi4*)(wlds + 1024 + lane * 16) = pc1;
            *(vf4*)szdst                     = psz0;
            *(vf4*)(szdst + 512)             = psz1;

            // prefetch next super-iteration's streams
            if (more) {
                pc0  = __builtin_nontemporal_load(codes4 + (gbase >> 1) + lane);
                pc1  = __builtin_nontemporal_load(codes4 + (gbase >> 1) + 64 + lane);
                psz0 = __builtin_nontemporal_load((const vf4*)(szsrc + gbase) + sl);
                psz1 = __builtin_nontemporal_load((const vf4*)(szsrc + gbase) + 32 + sl);
            }

            // ---- 8 code reads (pair-broadcast, 2-way = free) ----
            vi2 c0 = *(const vi2*)(wlds + (0 * 32 + pidx) * 8);
            vi2 c1 = *(const vi2*)(wlds + (1 * 32 + pidx) * 8);
            vi2 c2 = *(const vi2*)(wlds + (2 * 32 + pidx) * 8);
            vi2 c3 = *(const vi2*)(wlds + (3 * 32 + pidx) * 8);
            vi2 c4 = *(const vi2*)(wlds + (4 * 32 + pidx) * 8);
            vi2 c5 = *(const vi2*)(wlds + (5 * 32 + pidx) * 8);
            vi2 c6 = *(const vi2*)(wlds + (6 * 32 + pidx) * 8);
            vi2 c7 = *(const vi2*)(wlds + (7 * 32 + pidx) * 8);

            // ---- 8 gathers back-to-back into named regs ----
            vi4 e0 = *(const vi4*)(mycb + ((size_t)(unsigned)(half ? c0.y : c0.x) << 3));
            vi4 e1 = *(const vi4*)(mycb + ((size_t)(unsigned)(half ? c1.y : c1.x) << 3));
            vi4 e2 = *(const vi4*)(mycb + ((size_t)(unsigned)(half ? c2.y : c2.x) << 3));
            vi4 e3 = *(const vi4*)(mycb + ((size_t)(unsigned)(half ? c3.y : c3.x) << 3));
            vi4 e4 = *(const vi4*)(mycb + ((size_t)(unsigned)(half ? c4.y : c4.x) << 3));
            vi4 e5 = *(const vi4*)(mycb + ((size_t)(unsigned)(half ? c5.y : c5.x) << 3));
            vi4 e6 = *(const vi4*)(mycb + ((size_t)(unsigned)(half ? c6.y : c6.x) << 3));
            vi4 e7 = *(const vi4*)(mycb + ((size_t)(unsigned)(half ? c7.y : c7.x) << 3));

            float* ob = out + (size_t)gcur * 8 + pidx * 8 + hoff;

            // ---- consume in issue order (staged vmcnt waits) ----
            #pragma unroll
            for (int k = 0; k < 8; ++k) {
                vi4 e = (k == 0) ? e0 : (k == 1) ? e1 : (k == 2) ? e2 :
                        (k == 3) ? e3 : (k == 4) ? e4 : (k == 5) ? e5 :
                        (k == 6) ? e6 : e7;
                // exchange halves within the lane pair (even: cb0, odd: cb1)
                int send0 = half ? e.x : e.z;
                int send1 = half ? e.y : e.w;
                int own0  = half ? e.z : e.x;
                int own1  = half ? e.w : e.y;
                int recv0 = __shfl_xor(send0, 1);
                int recv1 = __shfl_xor(send1, 1);
                vh2 s0 = __builtin_bit_cast(vh2, own0) + __builtin_bit_cast(vh2, recv0);
                vh2 s1 = __builtin_bit_cast(vh2, own1) + __builtin_bit_cast(vh2, recv1);

                float s = *(const float*)(wlds + 2048 + (k * 32 + pidx) * 4);
                float z = *(const float*)(wlds + 3072 + (k * 32 + pidx) * 4);
                vf4 r;
                r.x = (float)s0.x * s + z;
                r.y = (float)s0.y * s + z;
                r.z = (float)s1.x * s + z;
                r.w = (float)s1.y * s + z;
                __builtin_nontemporal_store(r, (vf4*)(ob + k * 256));
            }
            if (!more) break;
        }
    }

    // tail: groups beyond the last full 256-chunk (none at this size; safety)
    const size_t CB1 = (size_t)65536 * 8;
    const long total_full = ((long)total >> 8) << 8;
    const int  gtid  = blockIdx.x * blockDim.x + threadIdx.x;
    const long pstep = (long)(gridDim.x * blockDim.x) >> 1;
    for (long g = total_full + (gtid >> 1); g < total; g += pstep) {
        vi2  c = *(const vi2*)(codes + (size_t)2 * g);
        float s = scales[g];
        float z = zeros[g];
        vf4 a0 = *(const vf4*)(cbs + ((size_t)c.x << 3) + hoff);
        vf4 a1 = *(const vf4*)(cbs + CB1 + ((size_t)c.y << 3) + hoff);
        vf4 r  = (a0 + a1) * s + z;
        __builtin_nontemporal_store(r, (vf4*)(out + (size_t)g * 8 + hoff));
    }
}

// ---------------- fallback (ws too small): r4 pair kernel -------------------
__global__ __launch_bounds__(256) void
dequant_f32(const int* __restrict__ codes,
            const float* __restrict__ cbs,
            const float* __restrict__ scales,
            const float* __restrict__ zeros,
            float* __restrict__ out,
            int total)
{
    const size_t CB1 = (size_t)65536 * 8;
    const vi2* codes2 = (const vi2*)codes;
    const int tid   = blockIdx.x * blockDim.x + threadIdx.x;
    const int half  = tid & 1;
    const int hoff  = half * 4;
    const int gstep = (gridDim.x * blockDim.x) >> 1;
    for (int g = tid >> 1; g < total; g += gstep) {
        vi2  c = __builtin_nontemporal_load(codes2 + g);
        float s = __builtin_nontemporal_load(scales + g);
        float z = __builtin_nontemporal_load(zeros + g);
        vf4 e0 = *(const vf4*)(cbs + ((size_t)c.x << 3) + hoff);
        vf4 e1 = *(const vf4*)(cbs + CB1 + ((size_t)c.y << 3) + hoff);
        vf4 r  = (e0 + e1) * s + z;
        __builtin_nontemporal_store(r, (vf4*)(out + (size_t)g * 8 + hoff));
    }
}

extern "C" void kernel_launch(void* const* d_in, const int* in_sizes, int n_in,
                              void* d_out, int out_size, void* d_ws, size_t ws_size,
                              hipStream_t stream) {
    const int*   codes     = (const int*)  d_in[0];
    const float* codebooks = (const float*)d_in[1];
    const float* scales    = (const float*)d_in[2];
    const float* zeros     = (const float*)d_in[3];
    float*       out       = (float*)d_out;

    const int total = in_sizes[0] / 2;           // number of groups
    const size_t cb16_bytes = (size_t)2 * 65536 * 8 * sizeof(_Float16); // 2 MB

    if (ws_size >= cb16_bytes) {
        _Float16* cb16 = (_Float16*)d_ws;
        repack_kernel<<<512, 256, 0, stream>>>(codebooks, cb16);
        dequant_fp16<<<2048, 256, 0, stream>>>(
            codes, cb16, codebooks, scales, zeros, out, total);
    } else {
        dequant_f32<<<2048, 256, 0, stream>>>(
            codes, codebooks, scales, zeros, out, total);
    }
}

// Round 12
// 141.682 us; speedup vs baseline: 1.2595x; 1.2595x over previous
//
#include <hip/hip_runtime.h>

// QuantizedWeight dequant:
//   out[g*8+j] = (cb[0, codes[g,0], j] + cb[1, codes[g,1], j]) * scales[g] + zeros[g]
//
// r12: within-probe A/B on gather cache policy. Exact r10 structure (512
// groups/wave/super-iter, 16 named-reg gathers, (256,4), fp16 codebook in
// d_ws, pair-lane role split + shfl_xor, half-wave split s/z streams, LDS
// staging, dense nt stores). Templated on NT: first half of the groups runs
// cached gathers, second half runs nontemporal gathers (L1-bypass probe).
// Readout = total duration (per-dispatch rows are masked by fillBuffer).

typedef float    vf4 __attribute__((ext_vector_type(4)));
typedef int      vi4 __attribute__((ext_vector_type(4)));
typedef int      vi2 __attribute__((ext_vector_type(2)));
typedef _Float16 vh2 __attribute__((ext_vector_type(2)));
typedef _Float16 vh8 __attribute__((ext_vector_type(8)));

// ---------------- repack: f32 codebooks -> fp16 copy in workspace ----------
__global__ __launch_bounds__(256) void
repack_kernel(const float* __restrict__ cbs, _Float16* __restrict__ cb16)
{
    const int i = blockIdx.x * blockDim.x + threadIdx.x;   // 131072 threads
    const vf4* in4 = (const vf4*)cbs;
    vf4 a = in4[2 * i];
    vf4 b = in4[2 * i + 1];
    vh8 h;
    h[0] = (_Float16)a.x; h[1] = (_Float16)a.y;
    h[2] = (_Float16)a.z; h[3] = (_Float16)a.w;
    h[4] = (_Float16)b.x; h[5] = (_Float16)b.y;
    h[6] = (_Float16)b.z; h[7] = (_Float16)b.w;
    *(vh8*)(cb16 + (size_t)8 * i) = h;
}

// ---------------- main fp16-gather kernel, 16-deep MLP, templated NT --------
template<bool NT>
__global__ __launch_bounds__(256, 4) void
dequant_fp16(const int* __restrict__ codes,
             const _Float16* __restrict__ cb16,   // [2][65536][8] fp16
             const float* __restrict__ scales,
             const float* __restrict__ zeros,
             float* __restrict__ out,
             long gstart, long gcount)             // group range [gstart, gstart+gcount)
{
    // per-wave 8 KB: [0,4096) codes int2[512]; [4096,6144) s[512]; [6144,8192) z[512]
    __shared__ __align__(16) char lds_raw[4 * 8192];
    const int lane = threadIdx.x & 63;
    const int wid  = threadIdx.x >> 6;
    char* wlds = lds_raw + wid * 8192;

    const int  nwaves = (gridDim.x * blockDim.x) >> 6;
    const int  wave   = (blockIdx.x * blockDim.x + threadIdx.x) >> 6;
    const long wstep  = (long)nwaves * 512;
    const long gend   = gstart + gcount;

    const vi4* codes4 = (const vi4*)codes;

    const int half = lane & 1;            // output half AND entry role
    const int hoff = half * 4;            // float offset of my output half
    const int pidx = lane >> 1;           // pair index 0..31
    const _Float16* mycb = cb16 + ((size_t)half << 19);  // cb1 base for odd lanes

    const float* szsrc = (lane < 32) ? scales : zeros;
    const int    sl    = lane & 31;
    char* szdst = wlds + 4096 + ((lane >> 5) << 11) + (sl << 4);

    // gather load with templated cache policy
    auto gld = [&](int code) -> vi4 {
        const vi4* p = (const vi4*)(mycb + ((size_t)(unsigned)code << 3));
        if constexpr (NT) return __builtin_nontemporal_load(p);
        else              return *p;
    };

    long gbase = gstart + (long)wave * 512;

    if (gbase + 512 <= gend) {
        // prologue stream loads (cover 512 groups)
        vi4 pc0  = __builtin_nontemporal_load(codes4 + (gbase >> 1) + lane);
        vi4 pc1  = __builtin_nontemporal_load(codes4 + (gbase >> 1) + 64 + lane);
        vi4 pc2  = __builtin_nontemporal_load(codes4 + (gbase >> 1) + 128 + lane);
        vi4 pc3  = __builtin_nontemporal_load(codes4 + (gbase >> 1) + 192 + lane);
        vf4 psz0 = __builtin_nontemporal_load((const vf4*)(szsrc + gbase) + sl);
        vf4 psz1 = __builtin_nontemporal_load((const vf4*)(szsrc + gbase) + 32 + sl);
        vf4 psz2 = __builtin_nontemporal_load((const vf4*)(szsrc + gbase) + 64 + sl);
        vf4 psz3 = __builtin_nontemporal_load((const vf4*)(szsrc + gbase) + 96 + sl);

        for (;;) {
            const long gcur = gbase;
            gbase += wstep;
            const bool more = (gbase + 512 <= gend);

            // stage current super-iteration (wave-synchronous, in-order DS)
            *(vi4*)(wlds + lane * 16)        = pc0;
            *(vi4*)(wlds + 1024 + lane * 16) = pc1;
            *(vi4*)(wlds + 2048 + lane * 16) = pc2;
            *(vi4*)(wlds + 3072 + lane * 16) = pc3;
            *(vf4*)szdst                     = psz0;
            *(vf4*)(szdst + 512)             = psz1;
            *(vf4*)(szdst + 1024)            = psz2;
            *(vf4*)(szdst + 1536)            = psz3;

            // prefetch next super-iteration's streams
            if (more) {
                pc0  = __builtin_nontemporal_load(codes4 + (gbase >> 1) + lane);
                pc1  = __builtin_nontemporal_load(codes4 + (gbase >> 1) + 64 + lane);
                pc2  = __builtin_nontemporal_load(codes4 + (gbase >> 1) + 128 + lane);
                pc3  = __builtin_nontemporal_load(codes4 + (gbase >> 1) + 192 + lane);
                psz0 = __builtin_nontemporal_load((const vf4*)(szsrc + gbase) + sl);
                psz1 = __builtin_nontemporal_load((const vf4*)(szsrc + gbase) + 32 + sl);
                psz2 = __builtin_nontemporal_load((const vf4*)(szsrc + gbase) + 64 + sl);
                psz3 = __builtin_nontemporal_load((const vf4*)(szsrc + gbase) + 96 + sl);
            }

            // ---- 16 code reads (pair-broadcast, 2-way = free) ----
            vi2 c0  = *(const vi2*)(wlds + (0  * 32 + pidx) * 8);
            vi2 c1  = *(const vi2*)(wlds + (1  * 32 + pidx) * 8);
            vi2 c2  = *(const vi2*)(wlds + (2  * 32 + pidx) * 8);
            vi2 c3  = *(const vi2*)(wlds + (3  * 32 + pidx) * 8);
            vi2 c4  = *(const vi2*)(wlds + (4  * 32 + pidx) * 8);
            vi2 c5  = *(const vi2*)(wlds + (5  * 32 + pidx) * 8);
            vi2 c6  = *(const vi2*)(wlds + (6  * 32 + pidx) * 8);
            vi2 c7  = *(const vi2*)(wlds + (7  * 32 + pidx) * 8);
            vi2 c8  = *(const vi2*)(wlds + (8  * 32 + pidx) * 8);
            vi2 c9  = *(const vi2*)(wlds + (9  * 32 + pidx) * 8);
            vi2 c10 = *(const vi2*)(wlds + (10 * 32 + pidx) * 8);
            vi2 c11 = *(const vi2*)(wlds + (11 * 32 + pidx) * 8);
            vi2 c12 = *(const vi2*)(wlds + (12 * 32 + pidx) * 8);
            vi2 c13 = *(const vi2*)(wlds + (13 * 32 + pidx) * 8);
            vi2 c14 = *(const vi2*)(wlds + (14 * 32 + pidx) * 8);
            vi2 c15 = *(const vi2*)(wlds + (15 * 32 + pidx) * 8);

            // ---- 16 gathers back-to-back into named regs (16-deep MLP) ----
            vi4 e0  = gld(half ? c0.y  : c0.x);
            vi4 e1  = gld(half ? c1.y  : c1.x);
            vi4 e2  = gld(half ? c2.y  : c2.x);
            vi4 e3  = gld(half ? c3.y  : c3.x);
            vi4 e4  = gld(half ? c4.y  : c4.x);
            vi4 e5  = gld(half ? c5.y  : c5.x);
            vi4 e6  = gld(half ? c6.y  : c6.x);
            vi4 e7  = gld(half ? c7.y  : c7.x);
            vi4 e8  = gld(half ? c8.y  : c8.x);
            vi4 e9  = gld(half ? c9.y  : c9.x);
            vi4 e10 = gld(half ? c10.y : c10.x);
            vi4 e11 = gld(half ? c11.y : c11.x);
            vi4 e12 = gld(half ? c12.y : c12.x);
            vi4 e13 = gld(half ? c13.y : c13.x);
            vi4 e14 = gld(half ? c14.y : c14.x);
            vi4 e15 = gld(half ? c15.y : c15.x);

            float* ob = out + (size_t)gcur * 8 + pidx * 8 + hoff;

            // ---- consume in issue order (staged vmcnt waits) ----
            #pragma unroll
            for (int k = 0; k < 16; ++k) {
                vi4 e = (k == 0)  ? e0  : (k == 1)  ? e1  : (k == 2)  ? e2  :
                        (k == 3)  ? e3  : (k == 4)  ? e4  : (k == 5)  ? e5  :
                        (k == 6)  ? e6  : (k == 7)  ? e7  : (k == 8)  ? e8  :
                        (k == 9)  ? e9  : (k == 10) ? e10 : (k == 11) ? e11 :
                        (k == 12) ? e12 : (k == 13) ? e13 : (k == 14) ? e14 : e15;
                // exchange halves within the lane pair (even: cb0, odd: cb1)
                int send0 = half ? e.x : e.z;
                int send1 = half ? e.y : e.w;
                int own0  = half ? e.z : e.x;
                int own1  = half ? e.w : e.y;
                int recv0 = __shfl_xor(send0, 1);
                int recv1 = __shfl_xor(send1, 1);
                vh2 s0 = __builtin_bit_cast(vh2, own0) + __builtin_bit_cast(vh2, recv0);
                vh2 s1 = __builtin_bit_cast(vh2, own1) + __builtin_bit_cast(vh2, recv1);

                float s = *(const float*)(wlds + 4096 + (k * 32 + pidx) * 4);
                float z = *(const float*)(wlds + 6144 + (k * 32 + pidx) * 4);
                vf4 r;
                r.x = (float)s0.x * s + z;
                r.y = (float)s0.y * s + z;
                r.z = (float)s1.x * s + z;
                r.w = (float)s1.y * s + z;
                __builtin_nontemporal_store(r, (vf4*)(ob + k * 256));
            }
            if (!more) break;
        }
    }

    // tail: groups beyond the last full 512-chunk of this range (none here)
    const long nfull = (gcount >> 9) << 9;
    const int  gtid  = blockIdx.x * blockDim.x + threadIdx.x;
    const long pstep = (long)(gridDim.x * blockDim.x) >> 1;
    for (long g = gstart + nfull + (gtid >> 1); g < gend; g += pstep) {
        vi2  c = *(const vi2*)(codes + (size_t)2 * g);
        float s = scales[g];
        float z = zeros[g];
        vi4 e = gld(half ? c.y : c.x);
        int send0 = half ? e.x : e.z;
        int send1 = half ? e.y : e.w;
        int own0  = half ? e.z : e.x;
        int own1  = half ? e.w : e.y;
        int recv0 = __shfl_xor(send0, 1);
        int recv1 = __shfl_xor(send1, 1);
        vh2 s0 = __builtin_bit_cast(vh2, own0) + __builtin_bit_cast(vh2, recv0);
        vh2 s1 = __builtin_bit_cast(vh2, own1) + __builtin_bit_cast(vh2, recv1);
        vf4 r;
        r.x = (float)s0.x * s + z;
        r.y = (float)s0.y * s + z;
        r.z = (float)s1.x * s + z;
        r.w = (float)s1.y * s + z;
        __builtin_nontemporal_store(r, (vf4*)(out + (size_t)g * 8 + hoff));
    }
}

// ---------------- fallback (ws too small): r4 pair kernel -------------------
__global__ __launch_bounds__(256) void
dequant_f32(const int* __restrict__ codes,
            const float* __restrict__ cbs,
            const float* __restrict__ scales,
            const float* __restrict__ zeros,
            float* __restrict__ out,
            int total)
{
    const size_t CB1 = (size_t)65536 * 8;
    const vi2* codes2 = (const vi2*)codes;
    const int tid   = blockIdx.x * blockDim.x + threadIdx.x;
    const int half  = tid & 1;
    const int hoff  = half * 4;
    const int gstep = (gridDim.x * blockDim.x) >> 1;
    for (int g = tid >> 1; g < total; g += gstep) {
        vi2  c = __builtin_nontemporal_load(codes2 + g);
        float s = __builtin_nontemporal_load(scales + g);
        float z = __builtin_nontemporal_load(zeros + g);
        vf4 e0 = *(const vf4*)(cbs + ((size_t)c.x << 3) + hoff);
        vf4 e1 = *(const vf4*)(cbs + CB1 + ((size_t)c.y << 3) + hoff);
        vf4 r  = (e0 + e1) * s + z;
        __builtin_nontemporal_store(r, (vf4*)(out + (size_t)g * 8 + hoff));
    }
}

extern "C" void kernel_launch(void* const* d_in, const int* in_sizes, int n_in,
                              void* d_out, int out_size, void* d_ws, size_t ws_size,
                              hipStream_t stream) {
    const int*   codes     = (const int*)  d_in[0];
    const float* codebooks = (const float*)d_in[1];
    const float* scales    = (const float*)d_in[2];
    const float* zeros     = (const float*)d_in[3];
    float*       out       = (float*)d_out;

    const long total = in_sizes[0] / 2;          // number of groups
    const size_t cb16_bytes = (size_t)2 * 65536 * 8 * sizeof(_Float16); // 2 MB

    if (ws_size >= cb16_bytes) {
        _Float16* cb16 = (_Float16*)d_ws;
        repack_kernel<<<512, 256, 0, stream>>>(codebooks, cb16);
        // A/B split: first half cached gathers, second half nontemporal gathers
        long h = (total / 2) & ~511L;            // multiple of 512
        dequant_fp16<false><<<2048, 256, 0, stream>>>(
            codes, cb16, scales, zeros, out, 0L, h);
        dequant_fp16<true><<<2048, 256, 0, stream>>>(
            codes, cb16, scales, zeros, out, h, total - h);
    } else {
        dequant_f32<<<2048, 256, 0, stream>>>(
            codes, codebooks, scales, zeros, out, (int)total);
    }
}

// Round 13
// 127.814 us; speedup vs baseline: 1.3961x; 1.1085x over previous
//
#include <hip/hip_runtime.h>

// QuantizedWeight dequant:
//   out[g*8+j] = (cb[0, codes[g,0], j] + cb[1, codes[g,1], j]) * scales[g] + zeros[g]
//
// r13 = r10 reverted (best measured: 127.5 us; A/B in r12 showed nt gathers
// regress ~19%, so cached gathers are final).
// Structure: 512 groups/wave/super-iter, 16 named-reg gathers (16-deep MLP),
// fp16 codebook repacked into d_ws (entry = one dwordx4/lane), pair-lane role
// split + shfl_xor half exchange, half-wave split s/z streams, LDS staging,
// dense 16 B/lane nt stores, __launch_bounds__(256,4).
// Bottleneck (measured, 4-round stable): TCP unique-line processing,
// 2 lines/group (information floor) x ~4 cy/line/CU => ~125 us wall.

typedef float    vf4 __attribute__((ext_vector_type(4)));
typedef int      vi4 __attribute__((ext_vector_type(4)));
typedef int      vi2 __attribute__((ext_vector_type(2)));
typedef _Float16 vh2 __attribute__((ext_vector_type(2)));
typedef _Float16 vh8 __attribute__((ext_vector_type(8)));

// ---------------- repack: f32 codebooks -> fp16 copy in workspace ----------
__global__ __launch_bounds__(256) void
repack_kernel(const float* __restrict__ cbs, _Float16* __restrict__ cb16)
{
    const int i = blockIdx.x * blockDim.x + threadIdx.x;   // 131072 threads
    const vf4* in4 = (const vf4*)cbs;
    vf4 a = in4[2 * i];
    vf4 b = in4[2 * i + 1];
    vh8 h;
    h[0] = (_Float16)a.x; h[1] = (_Float16)a.y;
    h[2] = (_Float16)a.z; h[3] = (_Float16)a.w;
    h[4] = (_Float16)b.x; h[5] = (_Float16)b.y;
    h[6] = (_Float16)b.z; h[7] = (_Float16)b.w;
    *(vh8*)(cb16 + (size_t)8 * i) = h;
}

// ---------------- main fp16-gather kernel, 16-deep MLP ----------------------
__global__ __launch_bounds__(256, 4) void
dequant_fp16(const int* __restrict__ codes,
             const _Float16* __restrict__ cb16,   // [2][65536][8] fp16
             const float* __restrict__ cbs,       // f32 original (tail only)
             const float* __restrict__ scales,
             const float* __restrict__ zeros,
             float* __restrict__ out,
             int total)
{
    // per-wave 8 KB: [0,4096) codes int2[512]; [4096,6144) s[512]; [6144,8192) z[512]
    __shared__ __align__(16) char lds_raw[4 * 8192];
    const int lane = threadIdx.x & 63;
    const int wid  = threadIdx.x >> 6;
    char* wlds = lds_raw + wid * 8192;

    const int  nwaves = (gridDim.x * blockDim.x) >> 6;
    const int  wave   = (blockIdx.x * blockDim.x + threadIdx.x) >> 6;
    const long wstep  = (long)nwaves * 512;

    const vi4* codes4 = (const vi4*)codes;

    const int half = lane & 1;            // output half AND entry role
    const int hoff = half * 4;            // float offset of my output half
    const int pidx = lane >> 1;           // pair index 0..31
    const _Float16* mycb = cb16 + ((size_t)half << 19);  // cb1 base for odd lanes

    const float* szsrc = (lane < 32) ? scales : zeros;
    const int    sl    = lane & 31;
    char* szdst = wlds + 4096 + ((lane >> 5) << 11) + (sl << 4);

    long gbase = (long)wave * 512;

    if (gbase + 512 <= total) {
        // prologue stream loads (cover 512 groups)
        vi4 pc0  = __builtin_nontemporal_load(codes4 + (gbase >> 1) + lane);
        vi4 pc1  = __builtin_nontemporal_load(codes4 + (gbase >> 1) + 64 + lane);
        vi4 pc2  = __builtin_nontemporal_load(codes4 + (gbase >> 1) + 128 + lane);
        vi4 pc3  = __builtin_nontemporal_load(codes4 + (gbase >> 1) + 192 + lane);
        vf4 psz0 = __builtin_nontemporal_load((const vf4*)(szsrc + gbase) + sl);
        vf4 psz1 = __builtin_nontemporal_load((const vf4*)(szsrc + gbase) + 32 + sl);
        vf4 psz2 = __builtin_nontemporal_load((const vf4*)(szsrc + gbase) + 64 + sl);
        vf4 psz3 = __builtin_nontemporal_load((const vf4*)(szsrc + gbase) + 96 + sl);

        for (;;) {
            const long gcur = gbase;
            gbase += wstep;
            const bool more = (gbase + 512 <= total);

            // stage current super-iteration (wave-synchronous, in-order DS)
            *(vi4*)(wlds + lane * 16)        = pc0;
            *(vi4*)(wlds + 1024 + lane * 16) = pc1;
            *(vi4*)(wlds + 2048 + lane * 16) = pc2;
            *(vi4*)(wlds + 3072 + lane * 16) = pc3;
            *(vf4*)szdst                     = psz0;
            *(vf4*)(szdst + 512)             = psz1;
            *(vf4*)(szdst + 1024)            = psz2;
            *(vf4*)(szdst + 1536)            = psz3;

            // prefetch next super-iteration's streams
            if (more) {
                pc0  = __builtin_nontemporal_load(codes4 + (gbase >> 1) + lane);
                pc1  = __builtin_nontemporal_load(codes4 + (gbase >> 1) + 64 + lane);
                pc2  = __builtin_nontemporal_load(codes4 + (gbase >> 1) + 128 + lane);
                pc3  = __builtin_nontemporal_load(codes4 + (gbase >> 1) + 192 + lane);
                psz0 = __builtin_nontemporal_load((const vf4*)(szsrc + gbase) + sl);
                psz1 = __builtin_nontemporal_load((const vf4*)(szsrc + gbase) + 32 + sl);
                psz2 = __builtin_nontemporal_load((const vf4*)(szsrc + gbase) + 64 + sl);
                psz3 = __builtin_nontemporal_load((const vf4*)(szsrc + gbase) + 96 + sl);
            }

            // ---- 16 code reads (pair-broadcast, 2-way = free) ----
            vi2 c0  = *(const vi2*)(wlds + (0  * 32 + pidx) * 8);
            vi2 c1  = *(const vi2*)(wlds + (1  * 32 + pidx) * 8);
            vi2 c2  = *(const vi2*)(wlds + (2  * 32 + pidx) * 8);
            vi2 c3  = *(const vi2*)(wlds + (3  * 32 + pidx) * 8);
            vi2 c4  = *(const vi2*)(wlds + (4  * 32 + pidx) * 8);
            vi2 c5  = *(const vi2*)(wlds + (5  * 32 + pidx) * 8);
            vi2 c6  = *(const vi2*)(wlds + (6  * 32 + pidx) * 8);
            vi2 c7  = *(const vi2*)(wlds + (7  * 32 + pidx) * 8);
            vi2 c8  = *(const vi2*)(wlds + (8  * 32 + pidx) * 8);
            vi2 c9  = *(const vi2*)(wlds + (9  * 32 + pidx) * 8);
            vi2 c10 = *(const vi2*)(wlds + (10 * 32 + pidx) * 8);
            vi2 c11 = *(const vi2*)(wlds + (11 * 32 + pidx) * 8);
            vi2 c12 = *(const vi2*)(wlds + (12 * 32 + pidx) * 8);
            vi2 c13 = *(const vi2*)(wlds + (13 * 32 + pidx) * 8);
            vi2 c14 = *(const vi2*)(wlds + (14 * 32 + pidx) * 8);
            vi2 c15 = *(const vi2*)(wlds + (15 * 32 + pidx) * 8);

            // ---- 16 gathers back-to-back into named regs (16-deep MLP) ----
            vi4 e0  = *(const vi4*)(mycb + ((size_t)(unsigned)(half ? c0.y  : c0.x)  << 3));
            vi4 e1  = *(const vi4*)(mycb + ((size_t)(unsigned)(half ? c1.y  : c1.x)  << 3));
            vi4 e2  = *(const vi4*)(mycb + ((size_t)(unsigned)(half ? c2.y  : c2.x)  << 3));
            vi4 e3  = *(const vi4*)(mycb + ((size_t)(unsigned)(half ? c3.y  : c3.x)  << 3));
            vi4 e4  = *(const vi4*)(mycb + ((size_t)(unsigned)(half ? c4.y  : c4.x)  << 3));
            vi4 e5  = *(const vi4*)(mycb + ((size_t)(unsigned)(half ? c5.y  : c5.x)  << 3));
            vi4 e6  = *(const vi4*)(mycb + ((size_t)(unsigned)(half ? c6.y  : c6.x)  << 3));
            vi4 e7  = *(const vi4*)(mycb + ((size_t)(unsigned)(half ? c7.y  : c7.x)  << 3));
            vi4 e8  = *(const vi4*)(mycb + ((size_t)(unsigned)(half ? c8.y  : c8.x)  << 3));
            vi4 e9  = *(const vi4*)(mycb + ((size_t)(unsigned)(half ? c9.y  : c9.x)  << 3));
            vi4 e10 = *(const vi4*)(mycb + ((size_t)(unsigned)(half ? c10.y : c10.x) << 3));
            vi4 e11 = *(const vi4*)(mycb + ((size_t)(unsigned)(half ? c11.y : c11.x) << 3));
            vi4 e12 = *(const vi4*)(mycb + ((size_t)(unsigned)(half ? c12.y : c12.x) << 3));
            vi4 e13 = *(const vi4*)(mycb + ((size_t)(unsigned)(half ? c13.y : c13.x) << 3));
            vi4 e14 = *(const vi4*)(mycb + ((size_t)(unsigned)(half ? c14.y : c14.x) << 3));
            vi4 e15 = *(const vi4*)(mycb + ((size_t)(unsigned)(half ? c15.y : c15.x) << 3));

            float* ob = out + (size_t)gcur * 8 + pidx * 8 + hoff;

            // ---- consume in issue order (staged vmcnt waits) ----
            #pragma unroll
            for (int k = 0; k < 16; ++k) {
                vi4 e = (k == 0)  ? e0  : (k == 1)  ? e1  : (k == 2)  ? e2  :
                        (k == 3)  ? e3  : (k == 4)  ? e4  : (k == 5)  ? e5  :
                        (k == 6)  ? e6  : (k == 7)  ? e7  : (k == 8)  ? e8  :
                        (k == 9)  ? e9  : (k == 10) ? e10 : (k == 11) ? e11 :
                        (k == 12) ? e12 : (k == 13) ? e13 : (k == 14) ? e14 : e15;
                // exchange halves within the lane pair (even: cb0, odd: cb1)
                int send0 = half ? e.x : e.z;
                int send1 = half ? e.y : e.w;
                int own0  = half ? e.z : e.x;
                int own1  = half ? e.w : e.y;
                int recv0 = __shfl_xor(send0, 1);
                int recv1 = __shfl_xor(send1, 1);
                vh2 s0 = __builtin_bit_cast(vh2, own0) + __builtin_bit_cast(vh2, recv0);
                vh2 s1 = __builtin_bit_cast(vh2, own1) + __builtin_bit_cast(vh2, recv1);

                float s = *(const float*)(wlds + 4096 + (k * 32 + pidx) * 4);
                float z = *(const float*)(wlds + 6144 + (k * 32 + pidx) * 4);
                vf4 r;
                r.x = (float)s0.x * s + z;
                r.y = (float)s0.y * s + z;
                r.z = (float)s1.x * s + z;
                r.w = (float)s1.y * s + z;
                __builtin_nontemporal_store(r, (vf4*)(ob + k * 256));
            }
            if (!more) break;
        }
    }

    // tail: groups beyond the last full 512-chunk (none at this size; safety)
    const size_t CB1 = (size_t)65536 * 8;
    const long total_full = ((long)total >> 9) << 9;
    const int  gtid  = blockIdx.x * blockDim.x + threadIdx.x;
    const long pstep = (long)(gridDim.x * blockDim.x) >> 1;
    for (long g = total_full + (gtid >> 1); g < total; g += pstep) {
        vi2  c = *(const vi2*)(codes + (size_t)2 * g);
        float s = scales[g];
        float z = zeros[g];
        vf4 a0 = *(const vf4*)(cbs + ((size_t)c.x << 3) + hoff);
        vf4 a1 = *(const vf4*)(cbs + CB1 + ((size_t)c.y << 3) + hoff);
        vf4 r  = (a0 + a1) * s + z;
        __builtin_nontemporal_store(r, (vf4*)(out + (size_t)g * 8 + hoff));
    }
}

// ---------------- fallback (ws too small): r4 pair kernel -------------------
__global__ __launch_bounds__(256) void
dequant_f32(const int* __restrict__ codes,
            const float* __restrict__ cbs,
            const float* __restrict__ scales,
            const float* __restrict__ zeros,
            float* __restrict__ out,
            int total)
{
    const size_t CB1 = (size_t)65536 * 8;
    const vi2* codes2 = (const vi2*)codes;
    const int tid   = blockIdx.x * blockDim.x + threadIdx.x;
    const int half  = tid & 1;
    const int hoff  = half * 4;
    const int gstep = (gridDim.x * blockDim.x) >> 1;
    for (int g = tid >> 1; g < total; g += gstep) {
        vi2  c = __builtin_nontemporal_load(codes2 + g);
        float s = __builtin_nontemporal_load(scales + g);
        float z = __builtin_nontemporal_load(zeros + g);
        vf4 e0 = *(const vf4*)(cbs + ((size_t)c.x << 3) + hoff);
        vf4 e1 = *(const vf4*)(cbs + CB1 + ((size_t)c.y << 3) + hoff);
        vf4 r  = (e0 + e1) * s + z;
        __builtin_nontemporal_store(r, (vf4*)(out + (size_t)g * 8 + hoff));
    }
}

extern "C" void kernel_launch(void* const* d_in, const int* in_sizes, int n_in,
                              void* d_out, int out_size, void* d_ws, size_t ws_size,
                              hipStream_t stream) {
    const int*   codes     = (const int*)  d_in[0];
    const float* codebooks = (const float*)d_in[1];
    const float* scales    = (const float*)d_in[2];
    const float* zeros     = (const float*)d_in[3];
    float*       out       = (float*)d_out;

    const int total = in_sizes[0] / 2;           // number of groups
    const size_t cb16_bytes = (size_t)2 * 65536 * 8 * sizeof(_Float16); // 2 MB

    if (ws_size >= cb16_bytes) {
        _Float16* cb16 = (_Float16*)d_ws;
        repack_kernel<<<512, 256, 0, stream>>>(codebooks, cb16);
        dequant_fp16<<<2048, 256, 0, stream>>>(
            codes, cb16, codebooks, scales, zeros, out, total);
    } else {
        dequant_f32<<<2048, 256, 0, stream>>>(
            codes, codebooks, scales, zeros, out, total);
    }
}